// Round 2
// baseline (206.588 us; speedup 1.0000x reference)
//
#include <hip/hip_runtime.h>

#define B_   4
#define C_   256
#define CQ_  32
#define M_   8
#define MID_ 16
#define H_   56
#define W_   56
#define HW_  3136
#define K_   7
#define P_   (B_*HW_)   // 12544 total pixels

// ---------------- geometry prior: gpk[cq][i][j] (CQ*49 floats) ----------------
__global__ void gpk_kernel(const float* __restrict__ wg1, const float* __restrict__ bg1,
                           const float* __restrict__ wg2, const float* __restrict__ bg2,
                           float* __restrict__ gpk) {
    int idx = blockIdx.x * blockDim.x + threadIdx.x;
    if (idx >= CQ_ * K_ * K_) return;
    int cq = idx / 49;
    int ij = idx % 49;
    int i = ij / 7, j = ij % 7;
    float xp = (float)(j - 3);    // x position: -3..3 left->right
    float yp = (float)(3 - i);    // y position: 3..-3 top->bottom
    float acc = bg2[cq];
    #pragma unroll
    for (int o = 0; o < MID_; o++) {
        float g1 = wg1[o * 2 + 0] * xp + wg1[o * 2 + 1] * yp + bg1[o];
        g1 = fmaxf(g1, 0.0f);
        acc += wg2[cq * MID_ + o] * g1;
    }
    gpk[idx] = acc;
}

// ---------------- km/qm: 1x1 conv C -> CQ (both maps) ----------------
// grid: x = P_/256 pixels, y = 8 slot-groups (0..3 -> km cq 0..31, 4..7 -> qm)
__global__ void kq_kernel(const float* __restrict__ x,
                          const float* __restrict__ w_k, const float* __restrict__ b_k,
                          const float* __restrict__ w_q, const float* __restrict__ b_q,
                          float* __restrict__ km, float* __restrict__ qm) {
    int p  = blockIdx.x * blockDim.x + threadIdx.x;   // 0..P_-1
    int sg = blockIdx.y;                              // 0..7
    int b  = p / HW_;
    int hw = p % HW_;
    bool isQ = (sg >= 4);
    int cq0 = (sg & 3) * 8;
    const float* wrow = (isQ ? w_q : w_k) + cq0 * C_;
    const float* bias = (isQ ? b_q : b_k) + cq0;
    float* dst = isQ ? qm : km;

    float acc[8];
    #pragma unroll
    for (int r = 0; r < 8; r++) acc[r] = 0.0f;

    const float* xp = x + (size_t)b * C_ * HW_ + hw;
    for (int c = 0; c < C_; c++) {
        float xv = xp[c * HW_];
        #pragma unroll
        for (int r = 0; r < 8; r++)
            acc[r] += xv * wrow[r * C_ + c];   // uniform address -> scalar load
    }
    #pragma unroll
    for (int r = 0; r < 8; r++)
        dst[((b * CQ_ + cq0 + r) * HW_) + hw] = acc[r] + bias[r];
}

// ---------------- core: ak -> softmax(j) -> aggregate x over window ----------------
// grid: x = P_/256 pixels, y = CQ_
__global__ void core_kernel(const float* __restrict__ x,
                            const float* __restrict__ km, const float* __restrict__ qm,
                            const float* __restrict__ gpk, float* __restrict__ pre) {
    int p  = blockIdx.x * blockDim.x + threadIdx.x;
    int cq = blockIdx.y;
    int b  = p / HW_;
    int hw = p % HW_;
    int h  = hw / W_;
    int w  = hw % W_;

    float q = qm[(b * CQ_ + cq) * HW_ + hw];
    const float* gp  = gpk + cq * 49;
    const float* kmb = km + (size_t)(b * CQ_ + cq) * HW_;

    float ck[49];
    #pragma unroll
    for (int i = 0; i < K_; i++) {
        int hh = h + i - 3;
        bool hin = ((unsigned)hh < (unsigned)H_);
        float v[7];
        float mx = -1e30f;
        #pragma unroll
        for (int j = 0; j < K_; j++) {
            int ww = w + j - 3;
            // padded positions: km value is 0 (zero-pad AFTER conv+bias), logit = gpk only
            float kmv = (hin && (unsigned)ww < (unsigned)W_) ? kmb[hh * W_ + ww] : 0.0f;
            v[j] = kmv * q + gp[i * 7 + j];
            mx = fmaxf(mx, v[j]);
        }
        float s = 0.0f;
        #pragma unroll
        for (int j = 0; j < K_; j++) { v[j] = __expf(v[j] - mx); s += v[j]; }
        float inv = 1.0f / s;
        #pragma unroll
        for (int j = 0; j < K_; j++) ck[i * 7 + j] = v[j] * inv;
    }

    // aggregate: pre[b, m*CQ+cq, hw] = sum_{i,j} ck[i][j] * x[b, m*CQ+cq, neighbor]
    float acc[M_];
    #pragma unroll
    for (int m = 0; m < M_; m++) acc[m] = 0.0f;

    const float* xb = x + (size_t)b * C_ * HW_ + (size_t)cq * HW_;
    #pragma unroll
    for (int i = 0; i < K_; i++) {
        int hh = h + i - 3;
        if ((unsigned)hh >= (unsigned)H_) continue;
        #pragma unroll
        for (int j = 0; j < K_; j++) {
            int ww = w + j - 3;
            if ((unsigned)ww >= (unsigned)W_) continue;
            float c = ck[i * 7 + j];
            int off = hh * W_ + ww;
            #pragma unroll
            for (int m = 0; m < M_; m++)
                acc[m] += c * xb[(size_t)m * CQ_ * HW_ + off];
        }
    }
    #pragma unroll
    for (int m = 0; m < M_; m++)
        pre[((size_t)(b * C_ + m * CQ_ + cq) * HW_) + hw] = acc[m];
}

// ---------------- final 1x1 conv C -> C ----------------
// grid: x = P_/256 pixels, y = 32 (8 output channels each)
__global__ void fconv_kernel(const float* __restrict__ pre,
                             const float* __restrict__ w_f, const float* __restrict__ b_f,
                             float* __restrict__ out) {
    int p   = blockIdx.x * blockDim.x + threadIdx.x;
    int co0 = blockIdx.y * 8;
    int b   = p / HW_;
    int hw  = p % HW_;
    const float* pb = pre + (size_t)b * C_ * HW_ + hw;

    float acc[8];
    #pragma unroll
    for (int r = 0; r < 8; r++) acc[r] = 0.0f;

    for (int c = 0; c < C_; c++) {
        float pv = pb[c * HW_];
        #pragma unroll
        for (int r = 0; r < 8; r++)
            acc[r] += pv * w_f[(co0 + r) * C_ + c];  // uniform address -> scalar load
    }
    #pragma unroll
    for (int r = 0; r < 8; r++)
        out[((size_t)(b * C_ + co0 + r) * HW_) + hw] = acc[r] + b_f[co0 + r];
}

extern "C" void kernel_launch(void* const* d_in, const int* in_sizes, int n_in,
                              void* d_out, int out_size, void* d_ws, size_t ws_size,
                              hipStream_t stream) {
    const float* x    = (const float*)d_in[0];
    const float* w_k  = (const float*)d_in[1];
    const float* b_k  = (const float*)d_in[2];
    const float* w_q  = (const float*)d_in[3];
    const float* b_q  = (const float*)d_in[4];
    const float* w_g1 = (const float*)d_in[5];
    const float* b_g1 = (const float*)d_in[6];
    const float* w_g2 = (const float*)d_in[7];
    const float* b_g2 = (const float*)d_in[8];
    const float* w_f  = (const float*)d_in[9];
    const float* b_f  = (const float*)d_in[10];
    float* out = (float*)d_out;

    float* ws  = (float*)d_ws;
    float* km  = ws;                       // B*CQ*HW = 401408
    float* qm  = km + (B_ * CQ_ * HW_);    // 401408
    float* gpk = qm + (B_ * CQ_ * HW_);    // 1568
    float* pre = gpk + (CQ_ * K_ * K_);    // B*C*HW = 3211264

    gpk_kernel<<<dim3(7), 256, 0, stream>>>(w_g1, b_g1, w_g2, b_g2, gpk);
    kq_kernel<<<dim3(P_ / 256, 8), 256, 0, stream>>>(x, w_k, b_k, w_q, b_q, km, qm);
    core_kernel<<<dim3(P_ / 256, CQ_), 256, 0, stream>>>(x, km, qm, gpk, pre);
    fconv_kernel<<<dim3(P_ / 256, C_ / 8), 256, 0, stream>>>(pre, w_f, b_f, out);
}

// Round 3
// 171.718 us; speedup vs baseline: 1.2031x; 1.2031x over previous
//
#include <hip/hip_runtime.h>
#include <hip/hip_bf16.h>

typedef __hip_bfloat16 bf16;
typedef __attribute__((ext_vector_type(8))) short short8;
typedef __attribute__((ext_vector_type(4))) float floatx4;

#define B_   4
#define C_   256
#define CQ_  32
#define M_   8
#define MID_ 16
#define H_   56
#define W_   56
#define HW_  3136
#define K_   7
#define P_   (B_*HW_)   // 12544 total pixels

// ---------------- geometry prior: gpk[cq][i][j] (CQ*49 floats) ----------------
__global__ void gpk_kernel(const float* __restrict__ wg1, const float* __restrict__ bg1,
                           const float* __restrict__ wg2, const float* __restrict__ bg2,
                           float* __restrict__ gpk) {
    int idx = blockIdx.x * blockDim.x + threadIdx.x;
    if (idx >= CQ_ * K_ * K_) return;
    int cq = idx / 49;
    int ij = idx % 49;
    int i = ij / 7, j = ij % 7;
    float xp = (float)(j - 3);    // x position: -3..3 left->right
    float yp = (float)(3 - i);    // y position: 3..-3 top->bottom
    float acc = bg2[cq];
    #pragma unroll
    for (int o = 0; o < MID_; o++) {
        float g1 = wg1[o * 2 + 0] * xp + wg1[o * 2 + 1] * yp + bg1[o];
        g1 = fmaxf(g1, 0.0f);
        acc += wg2[cq * MID_ + o] * g1;
    }
    gpk[idx] = acc;
}

// ---------------- convert w_f (fp32) -> bf16, row-major [ch][k] ----------------
__global__ void wconv_kernel(const float* __restrict__ wf, bf16* __restrict__ wfb) {
    int i = blockIdx.x * 256 + threadIdx.x;   // 65536 total
    wfb[i] = __float2bfloat16(wf[i]);
}

// ---------------- km/qm: 1x1 conv C -> CQ (both maps) ----------------
// grid: x = P_/256 pixels, y = 8 slot-groups (0..3 -> km cq 0..31, 4..7 -> qm)
__global__ void kq_kernel(const float* __restrict__ x,
                          const float* __restrict__ w_k, const float* __restrict__ b_k,
                          const float* __restrict__ w_q, const float* __restrict__ b_q,
                          float* __restrict__ km, float* __restrict__ qm) {
    int p  = blockIdx.x * blockDim.x + threadIdx.x;   // 0..P_-1
    int sg = blockIdx.y;                              // 0..7
    int b  = p / HW_;
    int hw = p % HW_;
    bool isQ = (sg >= 4);
    int cq0 = (sg & 3) * 8;
    const float* wrow = (isQ ? w_q : w_k) + cq0 * C_;
    const float* bias = (isQ ? b_q : b_k) + cq0;
    float* dst = isQ ? qm : km;

    float acc[8];
    #pragma unroll
    for (int r = 0; r < 8; r++) acc[r] = 0.0f;

    const float* xp = x + (size_t)b * C_ * HW_ + hw;
    for (int c = 0; c < C_; c++) {
        float xv = xp[c * HW_];
        #pragma unroll
        for (int r = 0; r < 8; r++)
            acc[r] += xv * wrow[r * C_ + c];   // uniform address -> scalar load
    }
    #pragma unroll
    for (int r = 0; r < 8; r++)
        dst[((b * CQ_ + cq0 + r) * HW_) + hw] = acc[r] + bias[r];
}

// ---------------- core: ak -> softmax(j) -> aggregate x over window ----------------
// grid: x = P_/256 pixels, y = CQ_   (writes pre as bf16 now)
__global__ void core_kernel(const float* __restrict__ x,
                            const float* __restrict__ km, const float* __restrict__ qm,
                            const float* __restrict__ gpk, bf16* __restrict__ pre) {
    int p  = blockIdx.x * blockDim.x + threadIdx.x;
    int cq = blockIdx.y;
    int b  = p / HW_;
    int hw = p % HW_;
    int h  = hw / W_;
    int w  = hw % W_;

    float q = qm[(b * CQ_ + cq) * HW_ + hw];
    const float* gp  = gpk + cq * 49;
    const float* kmb = km + (size_t)(b * CQ_ + cq) * HW_;

    float ck[49];
    #pragma unroll
    for (int i = 0; i < K_; i++) {
        int hh = h + i - 3;
        bool hin = ((unsigned)hh < (unsigned)H_);
        float v[7];
        float mx = -1e30f;
        #pragma unroll
        for (int j = 0; j < K_; j++) {
            int ww = w + j - 3;
            // padded positions: km value is 0 (zero-pad AFTER conv+bias), logit = gpk only
            float kmv = (hin && (unsigned)ww < (unsigned)W_) ? kmb[hh * W_ + ww] : 0.0f;
            v[j] = kmv * q + gp[i * 7 + j];
            mx = fmaxf(mx, v[j]);
        }
        float s = 0.0f;
        #pragma unroll
        for (int j = 0; j < K_; j++) { v[j] = __expf(v[j] - mx); s += v[j]; }
        float inv = 1.0f / s;
        #pragma unroll
        for (int j = 0; j < K_; j++) ck[i * 7 + j] = v[j] * inv;
    }

    // aggregate: pre[b, m*CQ+cq, hw] = sum_{i,j} ck[i][j] * x[b, m*CQ+cq, neighbor]
    float acc[M_];
    #pragma unroll
    for (int m = 0; m < M_; m++) acc[m] = 0.0f;

    const float* xb = x + (size_t)b * C_ * HW_ + (size_t)cq * HW_;
    #pragma unroll
    for (int i = 0; i < K_; i++) {
        int hh = h + i - 3;
        if ((unsigned)hh >= (unsigned)H_) continue;
        #pragma unroll
        for (int j = 0; j < K_; j++) {
            int ww = w + j - 3;
            if ((unsigned)ww >= (unsigned)W_) continue;
            float c = ck[i * 7 + j];
            int off = hh * W_ + ww;
            #pragma unroll
            for (int m = 0; m < M_; m++)
                acc[m] += c * xb[(size_t)m * CQ_ * HW_ + off];
        }
    }
    #pragma unroll
    for (int m = 0; m < M_; m++)
        pre[((size_t)(b * C_ + m * CQ_ + cq) * HW_) + hw] = __float2bfloat16(acc[m]);
}

// ---------------- final 1x1 conv C -> C via bf16 MFMA ----------------
// per batch: out[ch][hw] = sum_k wfb[ch][k] * pre_b[k][hw]  (M=256, N=3136, K=256)
// grid: (196 N-tiles of 16, 4 M-blocks of 64, 4 batches); block = 256 thr = 4 waves.
// Each wave: one 16(ch) x 16(hw) tile, K-loop of 8 mfma_f32_16x16x32_bf16.
__global__ void __launch_bounds__(256) fconv_mfma(const bf16* __restrict__ pre,
                                                  const bf16* __restrict__ wfb,
                                                  const float* __restrict__ b_f,
                                                  float* __restrict__ out) {
    // B-panel staged transposed: ldsb[n][k], padded row stride 33 short8 (=264 shorts)
    __shared__ short8 ldsb8[16 * 33];
    short* ldsb = (short*)ldsb8;

    int tn = blockIdx.x;          // hw tile
    int bm = blockIdx.y;          // 64-channel block
    int b  = blockIdx.z;          // batch
    int t  = threadIdx.x;
    int wave = t >> 6;
    int lane = t & 63;
    int hw0 = tn * 16;

    const bf16* preb = pre + (size_t)b * C_ * HW_;

    // stage B: pre_b[k][hw0+n] -> ldsb[n*264 + k]; 4096 elems, 16/thread
    {
        int n  = t & 15;
        int k0 = (t >> 4) * 16;
        #pragma unroll
        for (int kk = 0; kk < 16; kk++) {
            int k = k0 + kk;
            ldsb[n * 264 + k] = *(const short*)&preb[(size_t)k * HW_ + hw0 + n];
        }
    }
    __syncthreads();

    int quad = lane >> 4;
    int m0   = bm * 64 + wave * 16;
    int am   = m0 + (lane & 15);                       // A row for this lane
    const short* wrow = (const short*)wfb + am * C_ + quad * 8;
    const short* brow = ldsb + (lane & 15) * 264 + quad * 8;

    floatx4 acc = {0.f, 0.f, 0.f, 0.f};
    #pragma unroll
    for (int k0 = 0; k0 < C_; k0 += 32) {
        short8 af = *(const short8*)(wrow + k0);       // A[m=lane&15][k=quad*8+j]
        short8 bf = *(const short8*)(brow + k0);       // B[k=quad*8+j][n=lane&15]
        acc = __builtin_amdgcn_mfma_f32_16x16x32_bf16(af, bf, acc, 0, 0, 0);
    }

    // C/D: col(n)=lane&15, row(m)=quad*4+reg
    int n = lane & 15;
    #pragma unroll
    for (int r = 0; r < 4; r++) {
        int ch = m0 + quad * 4 + r;
        out[((size_t)b * C_ + ch) * HW_ + hw0 + n] = acc[r] + b_f[ch];
    }
}

extern "C" void kernel_launch(void* const* d_in, const int* in_sizes, int n_in,
                              void* d_out, int out_size, void* d_ws, size_t ws_size,
                              hipStream_t stream) {
    const float* x    = (const float*)d_in[0];
    const float* w_k  = (const float*)d_in[1];
    const float* b_k  = (const float*)d_in[2];
    const float* w_q  = (const float*)d_in[3];
    const float* b_q  = (const float*)d_in[4];
    const float* w_g1 = (const float*)d_in[5];
    const float* b_g1 = (const float*)d_in[6];
    const float* w_g2 = (const float*)d_in[7];
    const float* b_g2 = (const float*)d_in[8];
    const float* w_f  = (const float*)d_in[9];
    const float* b_f  = (const float*)d_in[10];
    float* out = (float*)d_out;

    float* ws  = (float*)d_ws;
    float* km  = ws;                         // B*CQ*HW = 401408 fp32
    float* qm  = km + (B_ * CQ_ * HW_);      // 401408 fp32
    float* gpk = qm + (B_ * CQ_ * HW_);      // 1568 fp32
    bf16*  wfb = (bf16*)(gpk + CQ_ * K_ * K_);   // 65536 bf16 (16B-aligned offset)
    bf16*  pre = wfb + C_ * C_;              // B*C*HW = 3211264 bf16

    gpk_kernel<<<dim3(7), 256, 0, stream>>>(w_g1, b_g1, w_g2, b_g2, gpk);
    wconv_kernel<<<dim3(C_ * C_ / 256), 256, 0, stream>>>(w_f, wfb);
    kq_kernel<<<dim3(P_ / 256, 8), 256, 0, stream>>>(x, w_k, b_k, w_q, b_q, km, qm);
    core_kernel<<<dim3(P_ / 256, CQ_), 256, 0, stream>>>(x, km, qm, gpk, pre);
    fconv_mfma<<<dim3(HW_ / 16, C_ / 64, B_), 256, 0, stream>>>(pre, wfb, b_f, out);
}

// Round 4
// 128.569 us; speedup vs baseline: 1.6068x; 1.3356x over previous
//
#include <hip/hip_runtime.h>
#include <hip/hip_bf16.h>

typedef __hip_bfloat16 bf16;
typedef __attribute__((ext_vector_type(8))) short short8;
typedef __attribute__((ext_vector_type(4))) float floatx4;

#define B_   4
#define C_   256
#define CQ_  32
#define M_   8
#define MID_ 16
#define H_   56
#define W_   56
#define HW_  3136
#define K_   7
#define P_   (B_*HW_)   // 12544 total pixels

__device__ __forceinline__ unsigned short f2bf(float f) {
    __hip_bfloat16 h = __float2bfloat16(f);
    return *(unsigned short*)&h;
}

// ---------------- geometry prior: gpk[cq][i][j] (CQ*49 floats) ----------------
__global__ void gpk_kernel(const float* __restrict__ wg1, const float* __restrict__ bg1,
                           const float* __restrict__ wg2, const float* __restrict__ bg2,
                           float* __restrict__ gpk) {
    int idx = blockIdx.x * blockDim.x + threadIdx.x;
    if (idx >= CQ_ * K_ * K_) return;
    int cq = idx / 49;
    int ij = idx % 49;
    int i = ij / 7, j = ij % 7;
    float xp = (float)(j - 3);    // x position: -3..3 left->right
    float yp = (float)(3 - i);    // y position: 3..-3 top->bottom
    float acc = bg2[cq];
    #pragma unroll
    for (int o = 0; o < MID_; o++) {
        float g1 = wg1[o * 2 + 0] * xp + wg1[o * 2 + 1] * yp + bg1[o];
        g1 = fmaxf(g1, 0.0f);
        acc += wg2[cq * MID_ + o] * g1;
    }
    gpk[idx] = acc;
}

// ---------------- convert weights fp32 -> bf16 ----------------
// wkqb[64][256]: rows 0-31 = w_k, rows 32-63 = w_q.  wfb[256][256] = w_f.
__global__ void wcvt_kernel(const float* __restrict__ wk, const float* __restrict__ wq,
                            const float* __restrict__ wf,
                            bf16* __restrict__ wkqb, bf16* __restrict__ wfb) {
    int i = blockIdx.x * 256 + threadIdx.x;   // 0 .. 81919
    if (i < 8192)        wkqb[i] = __float2bfloat16(wk[i]);
    else if (i < 16384)  wkqb[i] = __float2bfloat16(wq[i - 8192]);
    else                 wfb[i - 16384] = __float2bfloat16(wf[i - 16384]);
}

// ---------------- km/qm via MFMA: GEMM M=64(k|q), K=256, N=HW per batch ----------------
// grid (HW/32, B); block 256 = 4 waves; wave w owns rows m0=w*16, both 16-px subtiles.
__global__ void __launch_bounds__(256) kq_mfma(const float* __restrict__ x,
                                               const bf16* __restrict__ wkqb,
                                               const float* __restrict__ b_k,
                                               const float* __restrict__ b_q,
                                               float* __restrict__ km, float* __restrict__ qm) {
    __shared__ short ldsb[32 * 264];   // [n][k], stride 264 shorts (16B-aligned, conflict-free)
    int hw0 = blockIdx.x * 32;
    int b   = blockIdx.y;
    int t   = threadIdx.x;

    // stage x[b][k][hw0..hw0+31] -> bf16 ldsb[n][k]; thread=(n16,kp), k-pairs packed as b32
    {
        int n16 = t & 15, kp = t >> 4;           // kp 0..15
        const float* xb = x + (size_t)b * C_ * HW_ + hw0;
        #pragma unroll
        for (int nb = 0; nb < 2; nb++) {
            int n = nb * 16 + n16;
            #pragma unroll
            for (int it = 0; it < 8; it++) {
                int k = 2 * (kp + 16 * it);
                float lo = xb[(size_t)k * HW_ + n];
                float hi = xb[(size_t)(k + 1) * HW_ + n];
                unsigned int u = (unsigned int)f2bf(lo) | ((unsigned int)f2bf(hi) << 16);
                *(unsigned int*)&ldsb[n * 264 + k] = u;
            }
        }
    }
    __syncthreads();

    int wave = t >> 6, lane = t & 63;
    int quad = lane >> 4, nl = lane & 15;
    int m0 = wave * 16;
    const short* arow = (const short*)wkqb + (m0 + nl) * C_ + quad * 8;
    const short* br0  = ldsb + nl * 264 + quad * 8;
    const short* br1  = ldsb + (16 + nl) * 264 + quad * 8;

    floatx4 acc0 = {0.f, 0.f, 0.f, 0.f}, acc1 = {0.f, 0.f, 0.f, 0.f};
    #pragma unroll
    for (int k0 = 0; k0 < C_; k0 += 32) {
        short8 af = *(const short8*)(arow + k0);
        acc0 = __builtin_amdgcn_mfma_f32_16x16x32_bf16(af, *(const short8*)(br0 + k0), acc0, 0, 0, 0);
        acc1 = __builtin_amdgcn_mfma_f32_16x16x32_bf16(af, *(const short8*)(br1 + k0), acc1, 0, 0, 0);
    }

    #pragma unroll
    for (int r = 0; r < 4; r++) {
        int ch = m0 + quad * 4 + r;        // 0..63
        bool isK = (ch < 32);
        int c = isK ? ch : ch - 32;
        float bias = isK ? b_k[c] : b_q[c];
        float* dst = (isK ? km : qm) + ((size_t)b * CQ_ + c) * HW_ + hw0 + nl;
        dst[0]  = acc0[r] + bias;
        dst[16] = acc1[r] + bias;
    }
}

// ---------------- core: LDS-tiled softmax + aggregation ----------------
// grid (7 row-stripes, CQ, B); block 448 = 8 rows x 56 cols, 1 px/thread.
__global__ void __launch_bounds__(448) core_kernel(const float* __restrict__ x,
                                                   const float* __restrict__ km,
                                                   const float* __restrict__ qm,
                                                   const float* __restrict__ gpk,
                                                   bf16* __restrict__ pre) {
    __shared__ float kms[14 * 62];       // km halo tile (rows h0-3..h0+10, cols -3..58)
    __shared__ float xs[8 * 14 * 62];    // 8 m-channels of x, same halo

    int ht = blockIdx.x, cq = blockIdx.y, b = blockIdx.z;
    int h0 = ht * 8;
    int t  = threadIdx.x;

    const float* kmc = km + ((size_t)b * CQ_ + cq) * HW_;
    for (int idx = t; idx < 14 * 62; idx += 448) {
        int rr = idx / 62, cc = idx % 62;
        int gh = h0 + rr - 3, gw = cc - 3;
        kms[idx] = ((unsigned)gh < 56u && (unsigned)gw < 56u) ? kmc[gh * 56 + gw] : 0.f;
    }
    #pragma unroll
    for (int m = 0; m < 8; m++) {
        const float* xc = x + ((size_t)b * C_ + m * CQ_ + cq) * HW_;
        for (int idx = t; idx < 868; idx += 448) {
            int rr = idx / 62, cc = idx % 62;
            int gh = h0 + rr - 3, gw = cc - 3;
            xs[m * 868 + idx] = ((unsigned)gh < 56u && (unsigned)gw < 56u) ? xc[gh * 56 + gw] : 0.f;
        }
    }
    __syncthreads();

    int r = t / 56, w = t % 56;
    int h = h0 + r;
    float q = qm[((size_t)b * CQ_ + cq) * HW_ + h * 56 + w];
    const float* gp = gpk + cq * 49;     // wave-uniform -> scalar loads

    float ck[49];
    #pragma unroll
    for (int i = 0; i < K_; i++) {
        int base = (r + i) * 62 + w;
        float v[7];
        float mx = -1e30f;
        #pragma unroll
        for (int j = 0; j < K_; j++) {
            v[j] = kms[base + j] * q + gp[i * 7 + j];
            mx = fmaxf(mx, v[j]);
        }
        float s = 0.0f;
        #pragma unroll
        for (int j = 0; j < K_; j++) { v[j] = __expf(v[j] - mx); s += v[j]; }
        float inv = 1.0f / s;
        #pragma unroll
        for (int j = 0; j < K_; j++) ck[i * 7 + j] = v[j] * inv;
    }

    float acc[M_];
    #pragma unroll
    for (int m = 0; m < M_; m++) acc[m] = 0.0f;

    #pragma unroll
    for (int i = 0; i < K_; i++) {
        int base = (r + i) * 62 + w;
        #pragma unroll
        for (int j = 0; j < K_; j++) {
            float c = ck[i * 7 + j];
            int o = base + j;
            #pragma unroll
            for (int m = 0; m < M_; m++)
                acc[m] += c * xs[m * 868 + o];   // zero-padded halo: no branches needed
        }
    }
    #pragma unroll
    for (int m = 0; m < M_; m++)
        pre[((size_t)b * C_ + m * CQ_ + cq) * HW_ + h * 56 + w] = __float2bfloat16(acc[m]);
}

// ---------------- final 1x1 conv via MFMA: M=256, K=256, N=HW per batch ----------------
// grid (HW/64, 4 m-blocks, B); block 256 = 4 waves; wave owns 16 ch x 64 px.
__global__ void __launch_bounds__(256) fconv_mfma(const bf16* __restrict__ pre,
                                                  const bf16* __restrict__ wfb,
                                                  const float* __restrict__ b_f,
                                                  float* __restrict__ out) {
    __shared__ short ldsb[64 * 264];   // [n][k], stride 264 shorts
    int hw0 = blockIdx.x * 64;
    int bm  = blockIdx.y;
    int b   = blockIdx.z;
    int t   = threadIdx.x;

    const short* preb = (const short*)pre + (size_t)b * C_ * HW_;
    {
        int n16 = t & 15, kp = t >> 4;   // kp 0..15
        #pragma unroll
        for (int nb = 0; nb < 4; nb++) {
            int n = nb * 16 + n16;
            #pragma unroll
            for (int it = 0; it < 8; it++) {
                int k = 2 * (kp + 16 * it);
                unsigned short lo = (unsigned short)preb[(size_t)k * HW_ + hw0 + n];
                unsigned short hi = (unsigned short)preb[(size_t)(k + 1) * HW_ + hw0 + n];
                *(unsigned int*)&ldsb[n * 264 + k] = (unsigned int)lo | ((unsigned int)hi << 16);
            }
        }
    }
    __syncthreads();

    int wave = t >> 6, lane = t & 63;
    int quad = lane >> 4, nl = lane & 15;
    int m0 = bm * 64 + wave * 16;
    const short* arow = (const short*)wfb + (m0 + nl) * C_ + quad * 8;

    floatx4 acc[4];
    #pragma unroll
    for (int nt = 0; nt < 4; nt++) acc[nt] = (floatx4){0.f, 0.f, 0.f, 0.f};

    #pragma unroll
    for (int k0 = 0; k0 < C_; k0 += 32) {
        short8 af = *(const short8*)(arow + k0);
        #pragma unroll
        for (int nt = 0; nt < 4; nt++) {
            short8 bf = *(const short8*)(ldsb + (nt * 16 + nl) * 264 + quad * 8 + k0);
            acc[nt] = __builtin_amdgcn_mfma_f32_16x16x32_bf16(af, bf, acc[nt], 0, 0, 0);
        }
    }

    #pragma unroll
    for (int r = 0; r < 4; r++) {
        int ch = m0 + quad * 4 + r;
        float bias = b_f[ch];
        float* dst = out + ((size_t)b * C_ + ch) * HW_ + hw0 + nl;
        #pragma unroll
        for (int nt = 0; nt < 4; nt++)
            dst[nt * 16] = acc[nt][r] + bias;
    }
}

extern "C" void kernel_launch(void* const* d_in, const int* in_sizes, int n_in,
                              void* d_out, int out_size, void* d_ws, size_t ws_size,
                              hipStream_t stream) {
    const float* x    = (const float*)d_in[0];
    const float* w_k  = (const float*)d_in[1];
    const float* b_k  = (const float*)d_in[2];
    const float* w_q  = (const float*)d_in[3];
    const float* b_q  = (const float*)d_in[4];
    const float* w_g1 = (const float*)d_in[5];
    const float* b_g1 = (const float*)d_in[6];
    const float* w_g2 = (const float*)d_in[7];
    const float* b_g2 = (const float*)d_in[8];
    const float* w_f  = (const float*)d_in[9];
    const float* b_f  = (const float*)d_in[10];
    float* out = (float*)d_out;

    float* ws  = (float*)d_ws;
    float* km  = ws;                              // 401408 f32
    float* qm  = km + (size_t)B_ * CQ_ * HW_;     // 401408 f32
    float* gpk = qm + (size_t)B_ * CQ_ * HW_;     // 1568 f32
    bf16*  wkqb = (bf16*)(gpk + CQ_ * K_ * K_);   // 64*256 bf16
    bf16*  wfb  = wkqb + 64 * C_;                 // 256*256 bf16
    bf16*  pre  = wfb + C_ * C_;                  // B*C*HW bf16

    gpk_kernel<<<dim3(7), 256, 0, stream>>>(w_g1, b_g1, w_g2, b_g2, gpk);
    wcvt_kernel<<<dim3(320), 256, 0, stream>>>(w_k, w_q, w_f, wkqb, wfb);
    kq_mfma<<<dim3(HW_ / 32, B_), 256, 0, stream>>>(x, wkqb, b_k, b_q, km, qm);
    core_kernel<<<dim3(7, CQ_, B_), 448, 0, stream>>>(x, km, qm, gpk, pre);
    fconv_mfma<<<dim3(HW_ / 64, C_ / 64, B_), 256, 0, stream>>>(pre, wfb, b_f, out);
}

// Round 5
// 126.881 us; speedup vs baseline: 1.6282x; 1.0133x over previous
//
#include <hip/hip_runtime.h>
#include <hip/hip_bf16.h>

typedef __hip_bfloat16 bf16;
typedef __attribute__((ext_vector_type(8))) short short8;
typedef __attribute__((ext_vector_type(4))) float floatx4;

#define B_   4
#define C_   256
#define CQ_  32
#define M_   8
#define MID_ 16
#define H_   56
#define W_   56
#define HW_  3136
#define K_   7

__device__ __forceinline__ unsigned short f2bf(float f) {
    __hip_bfloat16 h = __float2bfloat16(f);
    return *(unsigned short*)&h;
}

// ---------------- setup: weight converts + geometry prior (merged) ----------------
// blocks 0-63: wkqb[64][256] (rows 0-31 w_k, 32-63 w_q)
// blocks 64-319: wfp[ch][kk], kk = cq*8+m permuted from w_f[ch][m*32+cq]
// blocks 320-326: gpk[cq][i][j]
__global__ void setup_kernel(const float* __restrict__ wk, const float* __restrict__ wq,
                             const float* __restrict__ wf,
                             const float* __restrict__ wg1, const float* __restrict__ bg1,
                             const float* __restrict__ wg2, const float* __restrict__ bg2,
                             bf16* __restrict__ wkqb, bf16* __restrict__ wfp,
                             float* __restrict__ gpk) {
    int bid = blockIdx.x, t = threadIdx.x;
    if (bid < 64) {
        int i = bid * 256 + t;
        wkqb[i] = __float2bfloat16(i < 8192 ? wk[i] : wq[i - 8192]);
    } else if (bid < 320) {
        int j  = (bid - 64) * 256 + t;
        int ch = j >> 8, kk = j & 255;
        int cq = kk >> 3, m = kk & 7;
        wfp[j] = __float2bfloat16(wf[ch * 256 + m * 32 + cq]);
    } else {
        int idx = (bid - 320) * 256 + t;
        if (idx >= CQ_ * 49) return;
        int cq = idx / 49, ij = idx % 49;
        int i = ij / 7, j = ij % 7;
        float xp = (float)(j - 3);
        float yp = (float)(3 - i);
        float acc = bg2[cq];
        #pragma unroll
        for (int o = 0; o < MID_; o++) {
            float g1 = wg1[o * 2 + 0] * xp + wg1[o * 2 + 1] * yp + bg1[o];
            acc += wg2[cq * MID_ + o] * fmaxf(g1, 0.0f);
        }
        gpk[idx] = acc;
    }
}

// ---------------- km/qm via MFMA, fp32 float4 staging + swizzled LDS transpose ----------------
// grid (HW/32, B); block 256 = 4 waves. Block: 64 rows (32 km + 32 qm) x 32 px.
__global__ void __launch_bounds__(256) kq_mfma(const float* __restrict__ x,
                                               const bf16* __restrict__ wkqb,
                                               const float* __restrict__ b_k,
                                               const float* __restrict__ b_q,
                                               float* __restrict__ km, float* __restrict__ qm) {
    __shared__ short lt[32 * 264];   // [px][c], 16B chunks swizzled by ((c8 + (px>>2)) & 31)
    int hw0 = blockIdx.x * 32;
    int b   = blockIdx.y;
    int t   = threadIdx.x;

    {   // stage x[b][c][hw0..hw0+31] -> bf16 lt; coalesced float4 global reads
        int pq = t & 7, cb = t >> 3;            // px-quad, c-pair index
        const float* xb = x + (size_t)b * C_ * HW_ + hw0 + pq * 4;
        #pragma unroll
        for (int ii = 0; ii < 4; ii++) {
            int c = ii * 64 + cb * 2;
            floatx4 fa = *(const floatx4*)(xb + (size_t)c * HW_);
            floatx4 fb = *(const floatx4*)(xb + (size_t)(c + 1) * HW_);
            int c8 = c >> 3, sub = c & 7;
            #pragma unroll
            for (int u = 0; u < 4; u++) {
                int px = pq * 4 + u;
                unsigned uu = (unsigned)f2bf(fa[u]) | ((unsigned)f2bf(fb[u]) << 16);
                int off = px * 264 + ((c8 + (px >> 2)) & 31) * 8 + sub;
                *(unsigned*)&lt[off] = uu;
            }
        }
    }
    __syncthreads();

    int wave = t >> 6, lane = t & 63, quad = lane >> 4, nl = lane & 15;
    int m0 = wave * 16;
    const short* arow = (const short*)wkqb + (m0 + nl) * C_ + quad * 8;
    short8 af[8];
    #pragma unroll
    for (int k0 = 0; k0 < 8; k0++) af[k0] = *(const short8*)(arow + k0 * 32);

    floatx4 acc[2];
    #pragma unroll
    for (int nt = 0; nt < 2; nt++) acc[nt] = (floatx4){0.f, 0.f, 0.f, 0.f};

    #pragma unroll
    for (int nt = 0; nt < 2; nt++) {
        int px = nt * 16 + nl;
        int prow = px * 264, sw = px >> 2;
        #pragma unroll
        for (int k0 = 0; k0 < 8; k0++) {
            int c8 = k0 * 4 + quad;
            short8 bf = *(const short8*)&lt[prow + ((c8 + sw) & 31) * 8];
            acc[nt] = __builtin_amdgcn_mfma_f32_16x16x32_bf16(af[k0], bf, acc[nt], 0, 0, 0);
        }
    }

    #pragma unroll
    for (int r = 0; r < 4; r++) {
        int ch = m0 + quad * 4 + r;       // 0..63
        bool isK = (ch < 32);
        int c = isK ? ch : ch - 32;
        float bias = isK ? b_k[c] : b_q[c];
        float* dst = (isK ? km : qm) + ((size_t)b * CQ_ + c) * HW_ + hw0 + nl;
        dst[0]  = acc[0][r] + bias;
        dst[16] = acc[1][r] + bias;
    }
}

// ---------------- core: softmax + aggregation, float4 LDS, permuted bf16 output ----------------
// grid (7 stripes, CQ, B); block 448 = 8 rows x 56 cols.
// pre_t[b][px][kk], kk = cq*8 + m  (channel = m*32+cq) -> one short8 store/thread.
__global__ void __launch_bounds__(448) core_kernel(const float* __restrict__ x,
                                                   const float* __restrict__ km,
                                                   const float* __restrict__ qm,
                                                   const float* __restrict__ gpk,
                                                   bf16* __restrict__ pret) {
    __shared__ float   kms[14 * 62];
    __shared__ floatx4 xs4[2][14 * 62];   // [g][halo pos]: g=0 -> m 0-3, g=1 -> m 4-7

    int ht = blockIdx.x, cq = blockIdx.y, b = blockIdx.z;
    int h0 = ht * 8, t = threadIdx.x;

    const float* kmc = km + ((size_t)b * CQ_ + cq) * HW_;
    for (int idx = t; idx < 868; idx += 448) {
        int rr = idx / 62, cc = idx % 62;
        int gh = h0 + rr - 3, gw = cc - 3;
        bool in = ((unsigned)gh < 56u) && ((unsigned)gw < 56u);
        int o = gh * 56 + gw;
        kms[idx] = in ? kmc[o] : 0.f;
        #pragma unroll
        for (int g = 0; g < 2; g++) {
            floatx4 v;
            #pragma unroll
            for (int mm = 0; mm < 4; mm++) {
                const float* xc = x + ((size_t)b * C_ + (g * 4 + mm) * CQ_ + cq) * HW_;
                v[mm] = in ? xc[o] : 0.f;
            }
            xs4[g][idx] = v;
        }
    }
    __syncthreads();

    int r = t / 56, w = t % 56, h = h0 + r;
    float q = qm[((size_t)b * CQ_ + cq) * HW_ + h * 56 + w];
    const float* gp = gpk + cq * 49;      // wave-uniform -> scalar loads

    float ck[49];
    #pragma unroll
    for (int i = 0; i < 7; i++) {
        int base = (r + i) * 62 + w;
        float v[7], s = 0.f;
        #pragma unroll
        for (int j = 0; j < 7; j++) {     // logits bounded (~|10|): exp safe without max-sub
            v[j] = __expf(kms[base + j] * q + gp[i * 7 + j]);
            s += v[j];
        }
        float inv = 1.0f / s;
        #pragma unroll
        for (int j = 0; j < 7; j++) ck[i * 7 + j] = v[j] * inv;
    }

    floatx4 a0 = {0.f, 0.f, 0.f, 0.f}, a1 = {0.f, 0.f, 0.f, 0.f};
    #pragma unroll
    for (int i = 0; i < 7; i++) {
        int base = (r + i) * 62 + w;
        #pragma unroll
        for (int j = 0; j < 7; j++) {
            float c = ck[i * 7 + j];
            a0 += c * xs4[0][base + j];   // ds_read_b128, 2-way (free)
            a1 += c * xs4[1][base + j];
        }
    }

    short8 o8;
    #pragma unroll
    for (int mm = 0; mm < 4; mm++) {
        o8[mm]     = (short)f2bf(a0[mm]);
        o8[mm + 4] = (short)f2bf(a1[mm]);
    }
    *(short8*)((short*)pret + ((size_t)b * HW_ + h * 56 + w) * C_ + cq * 8) = o8;
}

// ---------------- final 1x1 conv via MFMA, LDS-free (B-frags direct from pre_t) ----------------
// grid (HW/64, 4 ch-blocks, B); block 256 = 4 waves; wave = 16 ch x 64 px.
__global__ void __launch_bounds__(256) fconv_mfma(const bf16* __restrict__ pret,
                                                  const bf16* __restrict__ wfp,
                                                  const float* __restrict__ b_f,
                                                  float* __restrict__ out) {
    int hw0 = blockIdx.x * 64;
    int bm  = blockIdx.y;
    int b   = blockIdx.z;
    int t   = threadIdx.x, wave = t >> 6, lane = t & 63, quad = lane >> 4, nl = lane & 15;
    int m0  = bm * 64 + wave * 16;

    const short* arow = (const short*)wfp + (m0 + nl) * C_ + quad * 8;
    short8 af[8];
    #pragma unroll
    for (int k0 = 0; k0 < 8; k0++) af[k0] = *(const short8*)(arow + k0 * 32);

    floatx4 acc[4];
    #pragma unroll
    for (int nt = 0; nt < 4; nt++) acc[nt] = (floatx4){0.f, 0.f, 0.f, 0.f};

    const short* pb = (const short*)pret + ((size_t)b * HW_ + hw0 + nl) * C_ + quad * 8;
    #pragma unroll
    for (int nt = 0; nt < 4; nt++) {
        const short* bp = pb + (size_t)nt * 16 * C_;
        #pragma unroll
        for (int k0 = 0; k0 < 8; k0++)
            acc[nt] = __builtin_amdgcn_mfma_f32_16x16x32_bf16(af[k0], *(const short8*)(bp + k0 * 32),
                                                              acc[nt], 0, 0, 0);
    }

    #pragma unroll
    for (int r = 0; r < 4; r++) {
        int ch = m0 + quad * 4 + r;
        float bias = b_f[ch];
        float* dst = out + ((size_t)b * C_ + ch) * HW_ + hw0 + nl;
        #pragma unroll
        for (int nt = 0; nt < 4; nt++)
            dst[nt * 16] = acc[nt][r] + bias;
    }
}

extern "C" void kernel_launch(void* const* d_in, const int* in_sizes, int n_in,
                              void* d_out, int out_size, void* d_ws, size_t ws_size,
                              hipStream_t stream) {
    const float* x    = (const float*)d_in[0];
    const float* w_k  = (const float*)d_in[1];
    const float* b_k  = (const float*)d_in[2];
    const float* w_q  = (const float*)d_in[3];
    const float* b_q  = (const float*)d_in[4];
    const float* w_g1 = (const float*)d_in[5];
    const float* b_g1 = (const float*)d_in[6];
    const float* w_g2 = (const float*)d_in[7];
    const float* b_g2 = (const float*)d_in[8];
    const float* w_f  = (const float*)d_in[9];
    const float* b_f  = (const float*)d_in[10];
    float* out = (float*)d_out;

    float* ws   = (float*)d_ws;
    float* km   = ws;                              // 401408 f32
    float* qm   = km + (size_t)B_ * CQ_ * HW_;     // 401408 f32
    float* gpk  = qm + (size_t)B_ * CQ_ * HW_;     // 1568 f32
    bf16*  wkqb = (bf16*)(gpk + CQ_ * 49);         // 64*256 bf16
    bf16*  wfp  = wkqb + 64 * C_;                  // 256*256 bf16 (K-permuted w_f)
    bf16*  pret = wfp + C_ * C_;                   // B*HW*256 bf16, [b][px][kk]

    setup_kernel<<<dim3(327), 256, 0, stream>>>(w_k, w_q, w_f, w_g1, b_g1, w_g2, b_g2,
                                                wkqb, wfp, gpk);
    kq_mfma<<<dim3(HW_ / 32, B_), 256, 0, stream>>>(x, wkqb, b_k, b_q, km, qm);
    core_kernel<<<dim3(7, CQ_, B_), 448, 0, stream>>>(x, km, qm, gpk, pret);
    fconv_mfma<<<dim3(HW_ / 64, C_ / 64, B_), 256, 0, stream>>>(pret, wfp, b_f, out);
}